// Round 14
// baseline (167.211 us; speedup 1.0000x reference)
//
#include <hip/hip_runtime.h>
#include <math.h>

#define DD    512
#define NN    32768      // B*L nodes
#define EE    262144     // edges (without self loops)

typedef float f32x4 __attribute__((ext_vector_type(4)));
typedef __bf16 bf16x8 __attribute__((ext_vector_type(8)));

#define AS1 __attribute__((address_space(1)))
#define AS3 __attribute__((address_space(3)))

// ---------------- CSR build ----------------
__global__ void k_zero(int* __restrict__ cnt) {
    int i = blockIdx.x * 256 + threadIdx.x;
    if (i < NN) cnt[i] = 0;
}

__global__ void k_count(const int* __restrict__ dst, int* __restrict__ cnt) {
    int e = blockIdx.x * 256 + threadIdx.x;
    if (e < EE) atomicAdd(&cnt[dst[e]], 1);
}

__global__ __launch_bounds__(1024) void k_scan(
    const int* __restrict__ cnt, int* __restrict__ offs,
    int* __restrict__ cursor, float* __restrict__ dinv)
{
    __shared__ int part[1024];
    int t = threadIdx.x;
    int base = t * 32;
    int local[32];
    int s = 0;
#pragma unroll
    for (int i = 0; i < 32; ++i) { local[i] = s; s += cnt[base + i]; }
    part[t] = s;
    __syncthreads();
    for (int off = 1; off < 1024; off <<= 1) {
        int v = (t >= off) ? part[t - off] : 0;
        __syncthreads();
        part[t] += v;
        __syncthreads();
    }
    int prev = (t == 0) ? 0 : part[t - 1];
#pragma unroll
    for (int i = 0; i < 32; ++i) {
        int o = prev + local[i];
        offs[base + i] = o;
        cursor[base + i] = o;
        dinv[base + i] = rsqrtf((float)cnt[base + i] + 1.0f);
    }
    if (t == 1023) offs[NN] = part[1023];
}

__global__ void k_fill(const int* __restrict__ src, const int* __restrict__ dst,
                       int* __restrict__ cursor, int* __restrict__ csr) {
    int e = blockIdx.x * 256 + threadIdx.x;
    if (e < EE) {
        int d = dst[e];
        int p = atomicAdd(&cursor[d], 1);
        csr[p] = src[e];
    }
}

// ---------------- weight transpose + convert: Wt[n][k] = (bf16)W[k][n] ----------------
__global__ __launch_bounds__(256) void k_wt(const float* __restrict__ W1, const float* __restrict__ Wg,
                                            __bf16* __restrict__ W1t, __bf16* __restrict__ Wgt) {
    __shared__ float tile[32][33];
    const float* W = blockIdx.z ? Wg : W1;
    __bf16* Wt = blockIdx.z ? Wgt : W1t;
    int x0 = blockIdx.x * 32;   // n block
    int y0 = blockIdx.y * 32;   // k block
    int tx = threadIdx.x;       // 0..31
    for (int j = threadIdx.y; j < 32; j += 8)
        tile[j][tx] = W[(size_t)(y0 + j) * DD + x0 + tx];
    __syncthreads();
    for (int j = threadIdx.y; j < 32; j += 8)
        Wt[(size_t)(x0 + j) * DD + y0 + tx] = (__bf16)tile[tx][j];
}

// ---------------- 256x256 bf16 MFMA GEMM, BK=64, counted-vmcnt 2-barrier loop ----------------
// 8 waves (2m x 4n): wave tile 128x64, acc[8][4] f32x4 = 128 regs. 8 K-steps of 64.
// Per K-step per wave: 64 MFMA (~2500 cyc/SIMD) >> HBM latency -> staging fully hidden.
// LDS: A,B tiles as 16B chunks [gs(8)][idx(256)] (gs = k32grp*4 + slot): a wave's
// ds_read_b128 run of 16 lanes spans 256B contiguous -> 2-way bank alias (free, m136).
// gload_lds: linear dest chunks, source carries the (gs,idx) permutation.
// Staging waits: vmcnt(8) mid-loop (tile k+1 stays in flight), vmcnt(0) only last step.
// MODE 1: A fp32 (text), reg-staged halves + cvt; out = PReLU(BN(A@W1+b1)) bf16
// MODE 2: A bf16 (h), gload_lds;                  out = A@Wg bf16 (unscaled)
template <int MODE>
__global__ __launch_bounds__(512, 2) void k_gemm_256(
    const void* __restrict__ Ap,
    const __bf16* __restrict__ Wt,
    __bf16* __restrict__ Cout,
    const float* __restrict__ bias,
    const float* __restrict__ gamma, const float* __restrict__ beta,
    const float* __restrict__ mean, const float* __restrict__ var,
    const float* __restrict__ alphap)
{
    __shared__ __bf16 As[2][16384];   // 2 x 32KB
    __shared__ __bf16 Bs[2][16384];   // 2 x 32KB  (total 128KB)

    const int t    = threadIdx.x;
    const int lane = t & 63;
    const int wv   = t >> 6;
    const int l15  = lane & 15;
    const int lhi  = lane >> 4;
    const int work = ((blockIdx.x & 7) << 5) + (blockIdx.x >> 3);  // bijective 256; XCD-affine
    const int m0   = (work >> 1) * 256;     // 128 m-panels
    const int n0   = (work & 1) * 256;      // 2 n-slices (same panel pair on same XCD)
    const int wm   = (wv >> 2) * 128;       // 0 / 128
    const int wn   = (wv & 3) * 64;         // 0..192

    auto stageB = [&](int bb, int k0) {     // 4 gload_lds / thread
#pragma unroll
        for (int i = 0; i < 4; ++i) {
            int d = i * 512 + wv * 64 + lane;
            int c = d & 255, gs = d >> 8;
            const __bf16* g = Wt + (size_t)(n0 + c) * DD + k0 + (gs >> 2) * 32 + (gs & 3) * 8;
            __builtin_amdgcn_global_load_lds(
                (const AS1 unsigned int*)g,
                (AS3 unsigned int*)(&Bs[bb][(i * 512 + wv * 64) * 8]), 16, 0, 0);
        }
    };
    auto stageA2 = [&](int bb, int k0) {    // MODE2: 4 gload_lds / thread
        const __bf16* A = (const __bf16*)Ap;
#pragma unroll
        for (int i = 0; i < 4; ++i) {
            int d = i * 512 + wv * 64 + lane;
            int r = d & 255, gs = d >> 8;
            const __bf16* g = A + (size_t)(m0 + r) * DD + k0 + (gs >> 2) * 32 + (gs & 3) * 8;
            __builtin_amdgcn_global_load_lds(
                (const AS1 unsigned int*)g,
                (AS3 unsigned int*)(&As[bb][(i * 512 + wv * 64) * 8]), 16, 0, 0);
        }
    };
    float4 fa[2][2];                        // MODE1 half-slab staging (16 regs)
    auto loadAh = [&](int h, int k0) {
        const float* A = (const float*)Ap;
#pragma unroll
        for (int q = 0; q < 2; ++q) {
            int d = (h * 2 + q) * 512 + t;
            int r = d & 255, gs = d >> 8;
            const float* g = A + (size_t)(m0 + r) * DD + k0 + (gs >> 2) * 32 + (gs & 3) * 8;
            fa[q][0] = *(const float4*)g;
            fa[q][1] = *(const float4*)(g + 4);
        }
    };
    auto writeAh = [&](int h, int bb) {
#pragma unroll
        for (int q = 0; q < 2; ++q) {
            int d = (h * 2 + q) * 512 + t;
            bf16x8 o;
            o[0] = (__bf16)fa[q][0].x; o[1] = (__bf16)fa[q][0].y;
            o[2] = (__bf16)fa[q][0].z; o[3] = (__bf16)fa[q][0].w;
            o[4] = (__bf16)fa[q][1].x; o[5] = (__bf16)fa[q][1].y;
            o[6] = (__bf16)fa[q][1].z; o[7] = (__bf16)fa[q][1].w;
            *(bf16x8*)&As[bb][(size_t)d * 8] = o;
        }
    };

    // ---- prologue: K-tile 0 into buffer 0 ----
    if constexpr (MODE == 1) {
        loadAh(0, 0); writeAh(0, 0);
        loadAh(1, 0); writeAh(1, 0);
        stageB(0, 0);
        asm volatile("s_waitcnt vmcnt(0) lgkmcnt(0)" ::: "memory");
    } else {
        stageA2(0, 0); stageB(0, 0);
    }

    f32x4 acc[8][4] = {};

    // ---- K loop: 8 steps of 64 ----
#pragma unroll
    for (int kt = 0; kt < 8; ++kt) {
        const int cur = kt & 1, nxt = cur ^ 1;
        const int k1 = (kt + 1) * 64;

        // 1) issue next tile's staging
        if (kt < 7) {
            if constexpr (MODE == 1) { loadAh(0, k1); stageB(nxt, k1); }
            else                     { stageA2(nxt, k1); stageB(nxt, k1); }
        }

        // 2) counted wait for CURRENT tile (next tile's 8 stay in flight)
        if (kt < 7) asm volatile("s_waitcnt vmcnt(8)" ::: "memory");
        else        asm volatile("s_waitcnt vmcnt(0)" ::: "memory");
        __builtin_amdgcn_s_barrier();       // B1: cur tile ready
        asm volatile("" ::: "memory");

        // 3) compute: two k32-groups, 32 MFMA each
#pragma unroll
        for (int g = 0; g < 2; ++g) {
            bf16x8 af[8], bfr[4];
#pragma unroll
            for (int m = 0; m < 8; ++m)
                af[m] = *(const bf16x8*)&As[cur][((g * 4 + lhi) * 256 + wm + m * 16 + l15) * 8];
#pragma unroll
            for (int n = 0; n < 4; ++n)
                bfr[n] = *(const bf16x8*)&Bs[cur][((g * 4 + lhi) * 256 + wn + n * 16 + l15) * 8];
#pragma unroll
            for (int m = 0; m < 8; ++m)
#pragma unroll
                for (int n = 0; n < 4; ++n)
                    acc[m][n] = __builtin_amdgcn_mfma_f32_16x16x32_bf16(af[m], bfr[n], acc[m][n], 0, 0, 0);
            // MODE1: between the two groups, commit half 0 and fetch half 1
            if constexpr (MODE == 1) {
                if (g == 0 && kt < 7) { writeAh(0, nxt); loadAh(1, k1); }
            }
        }
        if constexpr (MODE == 1) {
            if (kt < 7) writeAh(1, nxt);
            asm volatile("s_waitcnt lgkmcnt(0)" ::: "memory");
        }

        // 4) B2: buffer-reuse fence (no global drain mid-loop)
        asm volatile("" ::: "memory");
        __builtin_amdgcn_s_barrier();
        asm volatile("" ::: "memory");
    }

    // ---- epilogue ----
#pragma unroll
    for (int n = 0; n < 4; ++n) {
        int col = n0 + wn + n * 16 + l15;
        float sc = 1.0f, tc = 0.0f, al = 0.0f;
        if constexpr (MODE == 1) {
            sc = gamma[col] * rsqrtf(var[col] + 1e-5f);
            tc = (bias[col] - mean[col]) * sc + beta[col];
            al = alphap[0];
        }
#pragma unroll
        for (int m = 0; m < 8; ++m) {
            int rowb = m0 + wm + m * 16 + (lhi << 2);
#pragma unroll
            for (int j = 0; j < 4; ++j) {
                float x = acc[m][n][j];
                if constexpr (MODE == 1) {
                    x = x * sc + tc;
                    x = (x >= 0.0f) ? x : al * x;
                }
                Cout[(size_t)(rowb + j) * DD + col] = (__bf16)x;
            }
        }
    }
}

// ---------------- fused gather (deg-weighted) + bias + PReLU + L2 norm + residual ----------------
// xws is UNSCALED h@Wg; per-source dinv applied here (wave-uniform scalar FMA).
__global__ __launch_bounds__(256) void k_gather_final(
    const int* __restrict__ offs, const int* __restrict__ csr,
    const __bf16* __restrict__ xws, const float* __restrict__ dinv,
    const float* __restrict__ bg, const float* __restrict__ alpha2,
    const float* __restrict__ text, float* __restrict__ out)
{
    int blk = blockIdx.x;                              // 0..8191
    int sb  = ((blk & 7) << 10) + (blk >> 3);          // XCD-chunked (bijective)
    int wave = threadIdx.x >> 6;
    int lane = threadIdx.x & 63;
    int node = sb * 4 + wave;
    int c = lane * 8;
    int beg = offs[node], end = offs[node + 1];
    int ne = end - beg;

    float dn = dinv[node];
    bf16x8 sv = *(const bf16x8*)(xws + (size_t)node * DD + c);   // self loop
    float a[8];
#pragma unroll
    for (int i = 0; i < 8; ++i) a[i] = dn * (float)sv[i];

    int k = 0;
    for (; k + 4 <= ne; k += 4) {
        int s0 = csr[beg + k + 0];
        int s1 = csr[beg + k + 1];
        int s2 = csr[beg + k + 2];
        int s3 = csr[beg + k + 3];
        float d0 = dinv[s0], d1 = dinv[s1], d2 = dinv[s2], d3 = dinv[s3];
        bf16x8 v0 = *(const bf16x8*)(xws + (size_t)s0 * DD + c);
        bf16x8 v1 = *(const bf16x8*)(xws + (size_t)s1 * DD + c);
        bf16x8 v2 = *(const bf16x8*)(xws + (size_t)s2 * DD + c);
        bf16x8 v3 = *(const bf16x8*)(xws + (size_t)s3 * DD + c);
#pragma unroll
        for (int i = 0; i < 8; ++i)
            a[i] += d0 * (float)v0[i] + d1 * (float)v1[i] + d2 * (float)v2[i] + d3 * (float)v3[i];
    }
    for (; k < ne; ++k) {
        int s = csr[beg + k];
        float ds_ = dinv[s];
        bf16x8 v = *(const bf16x8*)(xws + (size_t)s * DD + c);
#pragma unroll
        for (int i = 0; i < 8; ++i) a[i] += ds_ * (float)v[i];
    }

    float al = alpha2[0];
    float g[8];
    float ss = 0.0f;
#pragma unroll
    for (int i = 0; i < 8; ++i) {
        float x = a[i] * dn + bg[c + i];
        x = (x >= 0.0f) ? x : al * x;
        g[i] = x;
        ss += x * x;
    }
#pragma unroll
    for (int off = 1; off < 64; off <<= 1) ss += __shfl_xor(ss, off, 64);
    float inv = 1.0f / fmaxf(sqrtf(ss), 1e-12f);

    size_t base = (size_t)node * DD + c;
    float4 t0 = *(const float4*)&text[base];
    float4 t1 = *(const float4*)&text[base + 4];
    float4 o0, o1;
    o0.x = g[0] * inv + t0.x; o0.y = g[1] * inv + t0.y;
    o0.z = g[2] * inv + t0.z; o0.w = g[3] * inv + t0.w;
    o1.x = g[4] * inv + t1.x; o1.y = g[5] * inv + t1.y;
    o1.z = g[6] * inv + t1.z; o1.w = g[7] * inv + t1.w;
    *(float4*)&out[base]     = o0;
    *(float4*)&out[base + 4] = o1;
}

extern "C" void kernel_launch(void* const* d_in, const int* in_sizes, int n_in,
                              void* d_out, int out_size, void* d_ws, size_t ws_size,
                              hipStream_t stream) {
    const float* text   = (const float*)d_in[0];
    const int*   esrc   = (const int*)d_in[1];
    const int*   edst   = (const int*)d_in[2];
    const float* W1     = (const float*)d_in[3];
    const float* b1     = (const float*)d_in[4];
    const float* gamma  = (const float*)d_in[5];
    const float* beta   = (const float*)d_in[6];
    const float* rmean  = (const float*)d_in[7];
    const float* rvar   = (const float*)d_in[8];
    const float* alpha1 = (const float*)d_in[9];
    const float* Wg     = (const float*)d_in[10];
    const float* bg     = (const float*)d_in[11];
    const float* alpha2 = (const float*)d_in[12];
    float* out = (float*)d_out;

    // workspace layout (~66.5 MiB)
    char* p = (char*)d_ws;
    auto alloc = [&](size_t bytes) { char* r = p; p += (bytes + 255) & ~(size_t)255; return r; };
    int*    cnt     = (int*)alloc((size_t)NN * 4);
    int*    offs    = (int*)alloc((size_t)(NN + 1) * 4);
    int*    cursor  = (int*)alloc((size_t)NN * 4);
    float*  dinv    = (float*)alloc((size_t)NN * 4);
    int*    csr     = (int*)alloc((size_t)EE * 4);
    __bf16* W1t     = (__bf16*)alloc((size_t)DD * DD * 2);
    __bf16* Wgt     = (__bf16*)alloc((size_t)DD * DD * 2);
    __bf16* h_bf    = (__bf16*)alloc((size_t)NN * DD * 2);
    __bf16* xws     = (__bf16*)alloc((size_t)NN * DD * 2);

    // 1) CSR build + dinv
    k_zero<<<NN / 256, 256, 0, stream>>>(cnt);
    k_count<<<EE / 256, 256, 0, stream>>>(edst, cnt);
    k_scan<<<1, 1024, 0, stream>>>(cnt, offs, cursor, dinv);
    k_fill<<<EE / 256, 256, 0, stream>>>(esrc, edst, cursor, csr);

    // 2) weights -> bf16 [n][k]
    k_wt<<<dim3(16, 16, 2), dim3(32, 8), 0, stream>>>(W1, Wg, W1t, Wgt);

    // 3) h = PReLU(BN(text@W1 + b1))   [256x256 tile, fp32 A inline-cvt]
    k_gemm_256<1><<<256, 512, 0, stream>>>(text, W1t, h_bf, b1, gamma, beta, rmean, rvar, alpha1);

    // 4) xws = h@Wg                    [256x256 tile, unscaled bf16 out]
    k_gemm_256<2><<<256, 512, 0, stream>>>(h_bf, Wgt, xws, nullptr, nullptr, nullptr, nullptr, nullptr, nullptr);

    // 5) fused gather (deg-weighted) + epilogue + L2 norm + residual
    k_gather_final<<<NN / 4, 256, 0, stream>>>(offs, csr, xws, dinv, bg, alpha2, text, out);
}

// Round 15
// 158.305 us; speedup vs baseline: 1.0563x; 1.0563x over previous
//
#include <hip/hip_runtime.h>
#include <math.h>

#define DD    512
#define NN    32768      // B*L nodes
#define EE    262144     // edges (without self loops)

typedef float f32x4 __attribute__((ext_vector_type(4)));
typedef __bf16 bf16x8 __attribute__((ext_vector_type(8)));

#define AS1 __attribute__((address_space(1)))
#define AS3 __attribute__((address_space(3)))

// ---------------- CSR build ----------------
__global__ void k_zero(int* __restrict__ cnt) {
    int i = blockIdx.x * 256 + threadIdx.x;
    if (i < NN) cnt[i] = 0;
}

__global__ void k_count(const int* __restrict__ dst, int* __restrict__ cnt) {
    int e = blockIdx.x * 256 + threadIdx.x;
    if (e < EE) atomicAdd(&cnt[dst[e]], 1);
}

__global__ __launch_bounds__(1024) void k_scan(
    const int* __restrict__ cnt, int* __restrict__ offs,
    int* __restrict__ cursor, float* __restrict__ dinv)
{
    __shared__ int part[1024];
    int t = threadIdx.x;
    int base = t * 32;
    int local[32];
    int s = 0;
#pragma unroll
    for (int i = 0; i < 32; ++i) { local[i] = s; s += cnt[base + i]; }
    part[t] = s;
    __syncthreads();
    for (int off = 1; off < 1024; off <<= 1) {
        int v = (t >= off) ? part[t - off] : 0;
        __syncthreads();
        part[t] += v;
        __syncthreads();
    }
    int prev = (t == 0) ? 0 : part[t - 1];
#pragma unroll
    for (int i = 0; i < 32; ++i) {
        int o = prev + local[i];
        offs[base + i] = o;
        cursor[base + i] = o;
        dinv[base + i] = rsqrtf((float)cnt[base + i] + 1.0f);
    }
    if (t == 1023) offs[NN] = part[1023];
}

__global__ void k_fill(const int* __restrict__ src, const int* __restrict__ dst,
                       int* __restrict__ cursor, int* __restrict__ csr) {
    int e = blockIdx.x * 256 + threadIdx.x;
    if (e < EE) {
        int d = dst[e];
        int p = atomicAdd(&cursor[d], 1);
        csr[p] = src[e];
    }
}

// ---------------- weight transpose + convert: Wt[n][k] = (bf16)W[k][n] ----------------
__global__ __launch_bounds__(256) void k_wt(const float* __restrict__ W1, const float* __restrict__ Wg,
                                            __bf16* __restrict__ W1t, __bf16* __restrict__ Wgt) {
    __shared__ float tile[32][33];
    const float* W = blockIdx.z ? Wg : W1;
    __bf16* Wt = blockIdx.z ? Wgt : W1t;
    int x0 = blockIdx.x * 32;   // n block
    int y0 = blockIdx.y * 32;   // k block
    int tx = threadIdx.x;       // 0..31
    for (int j = threadIdx.y; j < 32; j += 8)
        tile[j][tx] = W[(size_t)(y0 + j) * DD + x0 + tx];
    __syncthreads();
    for (int j = threadIdx.y; j < 32; j += 8)
        Wt[(size_t)(x0 + j) * DD + y0 + tx] = (__bf16)tile[tx][j];
}

// ---------------- weight-stationary bf16 MFMA GEMM (r10/r13 structure, 2 blocks/CU) ----------------
// Block: 8 waves x 32 cols = 256-col n-slice; 128 rows via 4 m-tiles of 32.
// Grid 512 -> 2 blocks/CU: one block's MFMA stretch hides the other's barrier/staging.
// W slice per wave: 32 cols x 512 K in regs (wf[2][16] = 128 VGPR).
// A-slab LDS: chunk d = kf*128 + r*4 + s (16B chunks); chunk (kf,r,s) holds global
//   k-chunk kf*4 + (s ^ ((r>>1)&3)) of row r -> 0-conflict reads (verified r13),
//   lane-linear conflict-free staging writes (source carries inverse permutation).
// Stage-early: next m-tile's loads issued at loop top; __syncthreads drain at loop
// bottom is ~free (issue->barrier distance = full m-tile compute, ~2500 cyc).
// MODE 1: A fp32 (text), reg-stage + cvt; out = PReLU(BN(A@W1+b1)) bf16
// MODE 2: A bf16 (h), gload_lds;          out = A@Wg bf16 (unscaled)
template <int MODE>
__global__ __launch_bounds__(512, 2) void k_gemm_w(
    const void* __restrict__ Ap,
    const __bf16* __restrict__ Wt,
    __bf16* __restrict__ Cout,
    const float* __restrict__ bias,
    const float* __restrict__ gamma, const float* __restrict__ beta,
    const float* __restrict__ mean, const float* __restrict__ var,
    const float* __restrict__ alphap)
{
    __shared__ __bf16 slab[2][16384];   // 2 x 32KB

    const int t    = threadIdx.x;
    const int lane = t & 63;
    const int wv   = t >> 6;
    const int l15  = lane & 15;
    const int lhi  = lane >> 4;
    const int work = ((blockIdx.x & 7) << 6) + (blockIdx.x >> 3);  // bijective 512; XCD-affine
    const int nsl  = work & 1;
    const int mb   = work >> 1;                 // 0..255
    const int mbase   = mb * 128;               // 128-row panels
    const int colbase = nsl * 256 + wv * 32;

    // ---- one-time: W fragments into registers ----
    bf16x8 wf[2][16];
#pragma unroll
    for (int C = 0; C < 2; ++C)
#pragma unroll
        for (int kf = 0; kf < 16; ++kf) {
            int col = colbase + C * 16 + l15;
            wf[C][kf] = *(const bf16x8*)(Wt + (size_t)col * DD + kf * 32 + lhi * 8);
        }

    // ---- one-time: per-col epilogue constants (MODE1) ----
    float s0 = 0, s1 = 0, t0 = 0, t1 = 0, al = 0;
    if constexpr (MODE == 1) {
        int c0 = colbase + l15, c1 = c0 + 16;
        float r0 = rsqrtf(var[c0] + 1e-5f), r1 = rsqrtf(var[c1] + 1e-5f);
        s0 = gamma[c0] * r0;  s1 = gamma[c1] * r1;
        t0 = (bias[c0] - mean[c0]) * s0 + beta[c0];
        t1 = (bias[c1] - mean[c1]) * s1 + beta[c1];
        al = alphap[0];
    }

    float4 fa[4][2];   // MODE1 staging regs (4 chunks x 8 fp32)

    auto loadA1 = [&](int mt) {        // MODE1: global fp32 -> regs (chunk d = q*512+t)
        const float* A = (const float*)Ap;
#pragma unroll
        for (int q = 0; q < 4; ++q) {
            int d = q * 512 + t;
            int kf = d >> 7, r = (d >> 2) & 31, s = d & 3;
            int c = kf * 4 + (s ^ ((r >> 1) & 3));
            const float* g = A + (size_t)(mbase + mt * 32 + r) * DD + c * 8;
            fa[q][0] = *(const float4*)g;
            fa[q][1] = *(const float4*)(g + 4);
        }
    };
    auto writeA1 = [&](int bb) {       // cvt + lane-linear ds_write (conflict-free)
#pragma unroll
        for (int q = 0; q < 4; ++q) {
            int d = q * 512 + t;
            bf16x8 o;
            o[0] = (__bf16)fa[q][0].x; o[1] = (__bf16)fa[q][0].y;
            o[2] = (__bf16)fa[q][0].z; o[3] = (__bf16)fa[q][0].w;
            o[4] = (__bf16)fa[q][1].x; o[5] = (__bf16)fa[q][1].y;
            o[6] = (__bf16)fa[q][1].z; o[7] = (__bf16)fa[q][1].w;
            *(bf16x8*)&slab[bb][(size_t)d * 8] = o;
        }
    };
    auto stage2 = [&](int bb, int mt) { // MODE2: gload_lds, perm source, linear dest
        const __bf16* A = (const __bf16*)Ap;
#pragma unroll
        for (int q = 0; q < 4; ++q) {
            int d  = q * 512 + wv * 64 + lane;
            int kf = d >> 7, r = (d >> 2) & 31, s = d & 3;
            int c  = kf * 4 + (s ^ ((r >> 1) & 3));
            const __bf16* g = A + (size_t)(mbase + mt * 32 + r) * DD + c * 8;
            __builtin_amdgcn_global_load_lds(
                (const AS1 unsigned int*)g,
                (AS3 unsigned int*)(&slab[bb][(size_t)(q * 512 + wv * 64) * 8]), 16, 0, 0);
        }
    };

    // ---- prologue: slab 0 ----
    if constexpr (MODE == 1) { loadA1(0); writeA1(0); }
    else                     { stage2(0, 0); }
    __syncthreads();

    // ---- m-loop: 4 tiles of 32 rows ----
#pragma unroll
    for (int mt = 0; mt < 4; ++mt) {
        const int cur = mt & 1, nxt = cur ^ 1;

        // issue next slab's global loads (complete during this tile's compute)
        if (mt < 3) {
            if constexpr (MODE == 1) loadA1(mt + 1);
            else                     stage2(nxt, mt + 1);
        }

        // full-K register compute: 16 kfrags x (2 ds_read + 4 MFMA)
        f32x4 acc[2][2] = {};
        const __bf16* sl = &slab[cur][0];
#pragma unroll
        for (int kf = 0; kf < 16; ++kf) {
            int r0 = l15, r1 = 16 + l15;
            int sA = lhi ^ ((r0 >> 1) & 3);
            int sB = lhi ^ ((r1 >> 1) & 3);
            bf16x8 a0 = *(const bf16x8*)&sl[(kf * 128 + r0 * 4 + sA) * 8];
            bf16x8 a1 = *(const bf16x8*)&sl[(kf * 128 + r1 * 4 + sB) * 8];
            acc[0][0] = __builtin_amdgcn_mfma_f32_16x16x32_bf16(a0, wf[0][kf], acc[0][0], 0, 0, 0);
            acc[0][1] = __builtin_amdgcn_mfma_f32_16x16x32_bf16(a0, wf[1][kf], acc[0][1], 0, 0, 0);
            acc[1][0] = __builtin_amdgcn_mfma_f32_16x16x32_bf16(a1, wf[0][kf], acc[1][0], 0, 0, 0);
            acc[1][1] = __builtin_amdgcn_mfma_f32_16x16x32_bf16(a1, wf[1][kf], acc[1][1], 0, 0, 0);
        }

        // epilogue for this 32x32 wave tile
#pragma unroll
        for (int R = 0; R < 2; ++R)
#pragma unroll
            for (int C = 0; C < 2; ++C) {
                int col  = colbase + C * 16 + l15;
                int rowb = mbase + mt * 32 + R * 16 + (lhi << 2);
#pragma unroll
                for (int j = 0; j < 4; ++j) {
                    float x = acc[R][C][j];
                    if constexpr (MODE == 1) {
                        float ss = C ? s1 : s0, tt = C ? t1 : t0;
                        x = x * ss + tt;
                        x = (x >= 0.0f) ? x : al * x;
                    }
                    Cout[(size_t)(rowb + j) * DD + col] = (__bf16)x;
                }
            }

        // MODE1: convert+write next slab (fa's vmcnt wait hid under compute)
        if constexpr (MODE == 1) {
            if (mt < 3) writeA1(nxt);
        }

        __syncthreads();   // drain ~free: staging issued a full m-tile ago
    }
}

// ---------------- fused gather (deg-weighted) + bias + PReLU + L2 norm + residual ----------------
// xws is UNSCALED h@Wg; per-source dinv applied here (wave-uniform scalar FMA).
__global__ __launch_bounds__(256) void k_gather_final(
    const int* __restrict__ offs, const int* __restrict__ csr,
    const __bf16* __restrict__ xws, const float* __restrict__ dinv,
    const float* __restrict__ bg, const float* __restrict__ alpha2,
    const float* __restrict__ text, float* __restrict__ out)
{
    int blk = blockIdx.x;                              // 0..8191
    int sb  = ((blk & 7) << 10) + (blk >> 3);          // XCD-chunked (bijective)
    int wave = threadIdx.x >> 6;
    int lane = threadIdx.x & 63;
    int node = sb * 4 + wave;
    int c = lane * 8;
    int beg = offs[node], end = offs[node + 1];
    int ne = end - beg;

    float dn = dinv[node];
    bf16x8 sv = *(const bf16x8*)(xws + (size_t)node * DD + c);   // self loop
    float a[8];
#pragma unroll
    for (int i = 0; i < 8; ++i) a[i] = dn * (float)sv[i];

    int k = 0;
    for (; k + 4 <= ne; k += 4) {
        int s0 = csr[beg + k + 0];
        int s1 = csr[beg + k + 1];
        int s2 = csr[beg + k + 2];
        int s3 = csr[beg + k + 3];
        float d0 = dinv[s0], d1 = dinv[s1], d2 = dinv[s2], d3 = dinv[s3];
        bf16x8 v0 = *(const bf16x8*)(xws + (size_t)s0 * DD + c);
        bf16x8 v1 = *(const bf16x8*)(xws + (size_t)s1 * DD + c);
        bf16x8 v2 = *(const bf16x8*)(xws + (size_t)s2 * DD + c);
        bf16x8 v3 = *(const bf16x8*)(xws + (size_t)s3 * DD + c);
#pragma unroll
        for (int i = 0; i < 8; ++i)
            a[i] += d0 * (float)v0[i] + d1 * (float)v1[i] + d2 * (float)v2[i] + d3 * (float)v3[i];
    }
    for (; k < ne; ++k) {
        int s = csr[beg + k];
        float ds_ = dinv[s];
        bf16x8 v = *(const bf16x8*)(xws + (size_t)s * DD + c);
#pragma unroll
        for (int i = 0; i < 8; ++i) a[i] += ds_ * (float)v[i];
    }

    float al = alpha2[0];
    float g[8];
    float ss = 0.0f;
#pragma unroll
    for (int i = 0; i < 8; ++i) {
        float x = a[i] * dn + bg[c + i];
        x = (x >= 0.0f) ? x : al * x;
        g[i] = x;
        ss += x * x;
    }
#pragma unroll
    for (int off = 1; off < 64; off <<= 1) ss += __shfl_xor(ss, off, 64);
    float inv = 1.0f / fmaxf(sqrtf(ss), 1e-12f);

    size_t base = (size_t)node * DD + c;
    float4 t0 = *(const float4*)&text[base];
    float4 t1 = *(const float4*)&text[base + 4];
    float4 o0, o1;
    o0.x = g[0] * inv + t0.x; o0.y = g[1] * inv + t0.y;
    o0.z = g[2] * inv + t0.z; o0.w = g[3] * inv + t0.w;
    o1.x = g[4] * inv + t1.x; o1.y = g[5] * inv + t1.y;
    o1.z = g[6] * inv + t1.z; o1.w = g[7] * inv + t1.w;
    *(float4*)&out[base]     = o0;
    *(float4*)&out[base + 4] = o1;
}

extern "C" void kernel_launch(void* const* d_in, const int* in_sizes, int n_in,
                              void* d_out, int out_size, void* d_ws, size_t ws_size,
                              hipStream_t stream) {
    const float* text   = (const float*)d_in[0];
    const int*   esrc   = (const int*)d_in[1];
    const int*   edst   = (const int*)d_in[2];
    const float* W1     = (const float*)d_in[3];
    const float* b1     = (const float*)d_in[4];
    const float* gamma  = (const float*)d_in[5];
    const float* beta   = (const float*)d_in[6];
    const float* rmean  = (const float*)d_in[7];
    const float* rvar   = (const float*)d_in[8];
    const float* alpha1 = (const float*)d_in[9];
    const float* Wg     = (const float*)d_in[10];
    const float* bg     = (const float*)d_in[11];
    const float* alpha2 = (const float*)d_in[12];
    float* out = (float*)d_out;

    // workspace layout (~66.5 MiB)
    char* p = (char*)d_ws;
    auto alloc = [&](size_t bytes) { char* r = p; p += (bytes + 255) & ~(size_t)255; return r; };
    int*    cnt     = (int*)alloc((size_t)NN * 4);
    int*    offs    = (int*)alloc((size_t)(NN + 1) * 4);
    int*    cursor  = (int*)alloc((size_t)NN * 4);
    float*  dinv    = (float*)alloc((size_t)NN * 4);
    int*    csr     = (int*)alloc((size_t)EE * 4);
    __bf16* W1t     = (__bf16*)alloc((size_t)DD * DD * 2);
    __bf16* Wgt     = (__bf16*)alloc((size_t)DD * DD * 2);
    __bf16* h_bf    = (__bf16*)alloc((size_t)NN * DD * 2);
    __bf16* xws     = (__bf16*)alloc((size_t)NN * DD * 2);

    // 1) CSR build + dinv
    k_zero<<<NN / 256, 256, 0, stream>>>(cnt);
    k_count<<<EE / 256, 256, 0, stream>>>(edst, cnt);
    k_scan<<<1, 1024, 0, stream>>>(cnt, offs, cursor, dinv);
    k_fill<<<EE / 256, 256, 0, stream>>>(esrc, edst, cursor, csr);

    // 2) weights -> bf16 [n][k]
    k_wt<<<dim3(16, 16, 2), dim3(32, 8), 0, stream>>>(W1, Wg, W1t, Wgt);

    // 3) h = PReLU(BN(text@W1 + b1))   [weight-stationary, fp32 A inline-cvt]
    k_gemm_w<1><<<512, 512, 0, stream>>>(text, W1t, h_bf, b1, gamma, beta, rmean, rvar, alpha1);

    // 4) xws = h@Wg                    [weight-stationary, unscaled bf16 out]
    k_gemm_w<2><<<512, 512, 0, stream>>>(h_bf, Wgt, xws, nullptr, nullptr, nullptr, nullptr, nullptr, nullptr);

    // 5) fused gather (deg-weighted) + epilogue + L2 norm + residual
    k_gather_final<<<NN / 4, 256, 0, stream>>>(offs, csr, xws, dinv, bg, alpha2, text, out);
}

// Round 16
// 151.894 us; speedup vs baseline: 1.1008x; 1.0422x over previous
//
#include <hip/hip_runtime.h>
#include <math.h>

#define DD    512
#define NN    32768      // B*L nodes
#define EE    262144     // edges (without self loops)

typedef float f32x4 __attribute__((ext_vector_type(4)));
typedef __bf16 bf16x8 __attribute__((ext_vector_type(8)));

#define AS1 __attribute__((address_space(1)))
#define AS3 __attribute__((address_space(3)))

// ---------------- CSR build ----------------
__global__ void k_zero(int* __restrict__ cnt) {
    int i = blockIdx.x * 256 + threadIdx.x;
    if (i < NN) cnt[i] = 0;
}

__global__ void k_count(const int* __restrict__ dst, int* __restrict__ cnt) {
    int e = blockIdx.x * 256 + threadIdx.x;
    if (e < EE) atomicAdd(&cnt[dst[e]], 1);
}

__global__ __launch_bounds__(1024) void k_scan(
    const int* __restrict__ cnt, int* __restrict__ offs,
    int* __restrict__ cursor, float* __restrict__ dinv)
{
    __shared__ int part[1024];
    int t = threadIdx.x;
    int base = t * 32;
    int local[32];
    int s = 0;
#pragma unroll
    for (int i = 0; i < 32; ++i) { local[i] = s; s += cnt[base + i]; }
    part[t] = s;
    __syncthreads();
    for (int off = 1; off < 1024; off <<= 1) {
        int v = (t >= off) ? part[t - off] : 0;
        __syncthreads();
        part[t] += v;
        __syncthreads();
    }
    int prev = (t == 0) ? 0 : part[t - 1];
#pragma unroll
    for (int i = 0; i < 32; ++i) {
        int o = prev + local[i];
        offs[base + i] = o;
        cursor[base + i] = o;
        dinv[base + i] = rsqrtf((float)cnt[base + i] + 1.0f);
    }
    if (t == 1023) offs[NN] = part[1023];
}

__global__ void k_fill(const int* __restrict__ src, const int* __restrict__ dst,
                       int* __restrict__ cursor, int* __restrict__ csr) {
    int e = blockIdx.x * 256 + threadIdx.x;
    if (e < EE) {
        int d = dst[e];
        int p = atomicAdd(&cursor[d], 1);
        csr[p] = src[e];
    }
}

// ---------------- weight transpose + convert: Wt[n][k] = (bf16)W[k][n] ----------------
__global__ __launch_bounds__(256) void k_wt(const float* __restrict__ W1, const float* __restrict__ Wg,
                                            __bf16* __restrict__ W1t, __bf16* __restrict__ Wgt) {
    __shared__ float tile[32][33];
    const float* W = blockIdx.z ? Wg : W1;
    __bf16* Wt = blockIdx.z ? Wgt : W1t;
    int x0 = blockIdx.x * 32;   // n block
    int y0 = blockIdx.y * 32;   // k block
    int tx = threadIdx.x;       // 0..31
    for (int j = threadIdx.y; j < 32; j += 8)
        tile[j][tx] = W[(size_t)(y0 + j) * DD + x0 + tx];
    __syncthreads();
    for (int j = threadIdx.y; j < 32; j += 8)
        Wt[(size_t)(x0 + j) * DD + y0 + tx] = (__bf16)tile[tx][j];
}

// ---------------- weight-stationary bf16 MFMA GEMM (r10 structure + depth-2 prefetch + setprio) ----------------
// Block: 8 waves x 32 cols = 256-col n-slice; 256 rows via 8 m-tiles of 32. Grid 256 (1/CU).
// W slice per wave: 32 cols x 512 K in regs (wf[2][16] = 128 VGPR).
// A-slab LDS: chunk d = kf*128 + r*4 + s; chunk (kf,r,s) holds global k-chunk
//   kf*4 + (s ^ ((r>>1)&3)) of row r -> 0-conflict reads (verified r13), lane-linear writes.
// MODE 1: A fp32 (text), reg-stage depth-1 + cvt; out = PReLU(BN(A@W1+b1)) bf16
//   sync: lgkmcnt(0) + raw barrier per m-tile (no vmcnt drain; fa reg-deps wait loads).
// MODE 2: A bf16 (h), gload_lds, TRIPLE buffer, prefetch distance 2; counted vmcnt(4)
//   (never 0 mid-loop) + raw barrier -> staging gets 2 compute stretches to land.
// T5: setprio(1) around each 64-MFMA stretch.
template <int MODE>
__global__ __launch_bounds__(512, 2) void k_gemm_w(
    const void* __restrict__ Ap,
    const __bf16* __restrict__ Wt,
    __bf16* __restrict__ Cout,
    const float* __restrict__ bias,
    const float* __restrict__ gamma, const float* __restrict__ beta,
    const float* __restrict__ mean, const float* __restrict__ var,
    const float* __restrict__ alphap)
{
    __shared__ __bf16 slab[MODE == 1 ? 2 : 3][16384];   // 32KB each

    const int t    = threadIdx.x;
    const int lane = t & 63;
    const int wv   = t >> 6;
    const int l15  = lane & 15;
    const int lhi  = lane >> 4;
    const int work = ((blockIdx.x & 7) << 5) + (blockIdx.x >> 3);  // bijective 256; XCD-affine
    const int nsl  = work & 1;
    const int mb   = work >> 1;
    const int mbase   = mb * 256;
    const int colbase = nsl * 256 + wv * 32;

    // ---- one-time: W fragments into registers ----
    bf16x8 wf[2][16];
#pragma unroll
    for (int C = 0; C < 2; ++C)
#pragma unroll
        for (int kf = 0; kf < 16; ++kf) {
            int col = colbase + C * 16 + l15;
            wf[C][kf] = *(const bf16x8*)(Wt + (size_t)col * DD + kf * 32 + lhi * 8);
        }

    // ---- one-time: per-col epilogue constants (MODE1) ----
    float s0 = 0, s1 = 0, t0 = 0, t1 = 0, al = 0;
    if constexpr (MODE == 1) {
        int c0 = colbase + l15, c1 = c0 + 16;
        float r0 = rsqrtf(var[c0] + 1e-5f), r1 = rsqrtf(var[c1] + 1e-5f);
        s0 = gamma[c0] * r0;  s1 = gamma[c1] * r1;
        t0 = (bias[c0] - mean[c0]) * s0 + beta[c0];
        t1 = (bias[c1] - mean[c1]) * s1 + beta[c1];
        al = alphap[0];
    }

    float4 fa[4][2];   // MODE1 staging regs (4 chunks x 8 fp32)

    auto loadA1 = [&](int mt) {        // MODE1: global fp32 -> regs (chunk d = q*512+t)
        const float* A = (const float*)Ap;
#pragma unroll
        for (int q = 0; q < 4; ++q) {
            int d = q * 512 + t;
            int kf = d >> 7, r = (d >> 2) & 31, s = d & 3;
            int c = kf * 4 + (s ^ ((r >> 1) & 3));
            const float* g = A + (size_t)(mbase + mt * 32 + r) * DD + c * 8;
            fa[q][0] = *(const float4*)g;
            fa[q][1] = *(const float4*)(g + 4);
        }
    };
    auto writeA1 = [&](int bb) {       // cvt + lane-linear ds_write (conflict-free)
#pragma unroll
        for (int q = 0; q < 4; ++q) {
            int d = q * 512 + t;
            bf16x8 o;
            o[0] = (__bf16)fa[q][0].x; o[1] = (__bf16)fa[q][0].y;
            o[2] = (__bf16)fa[q][0].z; o[3] = (__bf16)fa[q][0].w;
            o[4] = (__bf16)fa[q][1].x; o[5] = (__bf16)fa[q][1].y;
            o[6] = (__bf16)fa[q][1].z; o[7] = (__bf16)fa[q][1].w;
            *(bf16x8*)&slab[bb][(size_t)d * 8] = o;
        }
    };
    auto stage2 = [&](int bb, int mt) { // MODE2: gload_lds, perm source, linear dest
        const __bf16* A = (const __bf16*)Ap;
#pragma unroll
        for (int q = 0; q < 4; ++q) {
            int d  = q * 512 + wv * 64 + lane;
            int kf = d >> 7, r = (d >> 2) & 31, s = d & 3;
            int c  = kf * 4 + (s ^ ((r >> 1) & 3));
            const __bf16* g = A + (size_t)(mbase + mt * 32 + r) * DD + c * 8;
            __builtin_amdgcn_global_load_lds(
                (const AS1 unsigned int*)g,
                (AS3 unsigned int*)(&slab[bb][(size_t)(q * 512 + wv * 64) * 8]), 16, 0, 0);
        }
    };

    // ---- prologue ----
    if constexpr (MODE == 1) {
        loadA1(0); writeA1(0);
        asm volatile("s_waitcnt lgkmcnt(0)" ::: "memory");
        __builtin_amdgcn_s_barrier();
    } else {
        stage2(0, 0);
        stage2(1, 1);
        asm volatile("s_waitcnt vmcnt(4)" ::: "memory");   // slab0 ready, slab1 in flight
        __builtin_amdgcn_s_barrier();
    }
    asm volatile("" ::: "memory");

    // ---- m-loop: 8 tiles of 32 rows ----
#pragma unroll
    for (int mt = 0; mt < 8; ++mt) {
        const int cur = (MODE == 1) ? (mt & 1) : (mt % 3);

        // A) issue staging for the look-ahead tile
        if constexpr (MODE == 1) {
            if (mt < 7) loadA1(mt + 1);
        } else {
            if (mt < 6) stage2((mt + 2) % 3, mt + 2);
        }

        // B) full-K register compute: 16 kfrags x (2 ds_read + 4 MFMA)
        f32x4 acc[2][2] = {};
        const __bf16* sl = &slab[cur][0];
        __builtin_amdgcn_s_setprio(1);
#pragma unroll
        for (int kf = 0; kf < 16; ++kf) {
            int r0 = l15, r1 = 16 + l15;
            int sA = lhi ^ ((r0 >> 1) & 3);
            int sB = lhi ^ ((r1 >> 1) & 3);
            bf16x8 a0 = *(const bf16x8*)&sl[(kf * 128 + r0 * 4 + sA) * 8];
            bf16x8 a1 = *(const bf16x8*)&sl[(kf * 128 + r1 * 4 + sB) * 8];
            acc[0][0] = __builtin_amdgcn_mfma_f32_16x16x32_bf16(a0, wf[0][kf], acc[0][0], 0, 0, 0);
            acc[0][1] = __builtin_amdgcn_mfma_f32_16x16x32_bf16(a0, wf[1][kf], acc[0][1], 0, 0, 0);
            acc[1][0] = __builtin_amdgcn_mfma_f32_16x16x32_bf16(a1, wf[0][kf], acc[1][0], 0, 0, 0);
            acc[1][1] = __builtin_amdgcn_mfma_f32_16x16x32_bf16(a1, wf[1][kf], acc[1][1], 0, 0, 0);
        }
        __builtin_amdgcn_s_setprio(0);

        // C) epilogue for this 32x32 wave tile
#pragma unroll
        for (int R = 0; R < 2; ++R)
#pragma unroll
            for (int C = 0; C < 2; ++C) {
                int col  = colbase + C * 16 + l15;
                int rowb = mbase + mt * 32 + R * 16 + (lhi << 2);
#pragma unroll
                for (int j = 0; j < 4; ++j) {
                    float x = acc[R][C][j];
                    if constexpr (MODE == 1) {
                        float ss = C ? s1 : s0, tt = C ? t1 : t0;
                        x = x * ss + tt;
                        x = (x >= 0.0f) ? x : al * x;
                    }
                    Cout[(size_t)(rowb + j) * DD + col] = (__bf16)x;
                }
            }

        // D) MODE1: cvt+write next slab; sync per m-tile
        if constexpr (MODE == 1) {
            if (mt < 7) {
                writeA1(mt & 1 ? 0 : 1);
                asm volatile("s_waitcnt lgkmcnt(0)" ::: "memory");
                __builtin_amdgcn_s_barrier();
            }
        } else {
            if (mt < 6)      asm volatile("s_waitcnt vmcnt(4)" ::: "memory");  // mt+1 landed; mt+2 in flight
            else if (mt == 6) asm volatile("s_waitcnt vmcnt(0)" ::: "memory"); // last prefetch drained (cheap)
            if (mt < 7) __builtin_amdgcn_s_barrier();
        }
        asm volatile("" ::: "memory");
    }
}

// ---------------- fused gather (deg-weighted) + bias + PReLU + L2 norm + residual ----------------
// xws is UNSCALED h@Wg; per-source dinv applied here (wave-uniform scalar FMA).
__global__ __launch_bounds__(256) void k_gather_final(
    const int* __restrict__ offs, const int* __restrict__ csr,
    const __bf16* __restrict__ xws, const float* __restrict__ dinv,
    const float* __restrict__ bg, const float* __restrict__ alpha2,
    const float* __restrict__ text, float* __restrict__ out)
{
    int blk = blockIdx.x;                              // 0..8191
    int sb  = ((blk & 7) << 10) + (blk >> 3);          // XCD-chunked (bijective)
    int wave = threadIdx.x >> 6;
    int lane = threadIdx.x & 63;
    int node = sb * 4 + wave;
    int c = lane * 8;
    int beg = offs[node], end = offs[node + 1];
    int ne = end - beg;

    float dn = dinv[node];
    bf16x8 sv = *(const bf16x8*)(xws + (size_t)node * DD + c);   // self loop
    float a[8];
#pragma unroll
    for (int i = 0; i < 8; ++i) a[i] = dn * (float)sv[i];

    int k = 0;
    for (; k + 4 <= ne; k += 4) {
        int s0 = csr[beg + k + 0];
        int s1 = csr[beg + k + 1];
        int s2 = csr[beg + k + 2];
        int s3 = csr[beg + k + 3];
        float d0 = dinv[s0], d1 = dinv[s1], d2 = dinv[s2], d3 = dinv[s3];
        bf16x8 v0 = *(const bf16x8*)(xws + (size_t)s0 * DD + c);
        bf16x8 v1 = *(const bf16x8*)(xws + (size_t)s1 * DD + c);
        bf16x8 v2 = *(const bf16x8*)(xws + (size_t)s2 * DD + c);
        bf16x8 v3 = *(const bf16x8*)(xws + (size_t)s3 * DD + c);
#pragma unroll
        for (int i = 0; i < 8; ++i)
            a[i] += d0 * (float)v0[i] + d1 * (float)v1[i] + d2 * (float)v2[i] + d3 * (float)v3[i];
    }
    for (; k < ne; ++k) {
        int s = csr[beg + k];
        float ds_ = dinv[s];
        bf16x8 v = *(const bf16x8*)(xws + (size_t)s * DD + c);
#pragma unroll
        for (int i = 0; i < 8; ++i) a[i] += ds_ * (float)v[i];
    }

    float al = alpha2[0];
    float g[8];
    float ss = 0.0f;
#pragma unroll
    for (int i = 0; i < 8; ++i) {
        float x = a[i] * dn + bg[c + i];
        x = (x >= 0.0f) ? x : al * x;
        g[i] = x;
        ss += x * x;
    }
#pragma unroll
    for (int off = 1; off < 64; off <<= 1) ss += __shfl_xor(ss, off, 64);
    float inv = 1.0f / fmaxf(sqrtf(ss), 1e-12f);

    size_t base = (size_t)node * DD + c;
    float4 t0 = *(const float4*)&text[base];
    float4 t1 = *(const float4*)&text[base + 4];
    float4 o0, o1;
    o0.x = g[0] * inv + t0.x; o0.y = g[1] * inv + t0.y;
    o0.z = g[2] * inv + t0.z; o0.w = g[3] * inv + t0.w;
    o1.x = g[4] * inv + t1.x; o1.y = g[5] * inv + t1.y;
    o1.z = g[6] * inv + t1.z; o1.w = g[7] * inv + t1.w;
    *(float4*)&out[base]     = o0;
    *(float4*)&out[base + 4] = o1;
}

extern "C" void kernel_launch(void* const* d_in, const int* in_sizes, int n_in,
                              void* d_out, int out_size, void* d_ws, size_t ws_size,
                              hipStream_t stream) {
    const float* text   = (const float*)d_in[0];
    const int*   esrc   = (const int*)d_in[1];
    const int*   edst   = (const int*)d_in[2];
    const float* W1     = (const float*)d_in[3];
    const float* b1     = (const float*)d_in[4];
    const float* gamma  = (const float*)d_in[5];
    const float* beta   = (const float*)d_in[6];
    const float* rmean  = (const float*)d_in[7];
    const float* rvar   = (const float*)d_in[8];
    const float* alpha1 = (const float*)d_in[9];
    const float* Wg     = (const float*)d_in[10];
    const float* bg     = (const float*)d_in[11];
    const float* alpha2 = (const float*)d_in[12];
    float* out = (float*)d_out;

    // workspace layout (~66.5 MiB)
    char* p = (char*)d_ws;
    auto alloc = [&](size_t bytes) { char* r = p; p += (bytes + 255) & ~(size_t)255; return r; };
    int*    cnt     = (int*)alloc((size_t)NN * 4);
    int*    offs    = (int*)alloc((size_t)(NN + 1) * 4);
    int*    cursor  = (int*)alloc((size_t)NN * 4);
    float*  dinv    = (float*)alloc((size_t)NN * 4);
    int*    csr     = (int*)alloc((size_t)EE * 4);
    __bf16* W1t     = (__bf16*)alloc((size_t)DD * DD * 2);
    __bf16* Wgt     = (__bf16*)alloc((size_t)DD * DD * 2);
    __bf16* h_bf    = (__bf16*)alloc((size_t)NN * DD * 2);
    __bf16* xws     = (__bf16*)alloc((size_t)NN * DD * 2);

    // 1) CSR build + dinv
    k_zero<<<NN / 256, 256, 0, stream>>>(cnt);
    k_count<<<EE / 256, 256, 0, stream>>>(edst, cnt);
    k_scan<<<1, 1024, 0, stream>>>(cnt, offs, cursor, dinv);
    k_fill<<<EE / 256, 256, 0, stream>>>(esrc, edst, cursor, csr);

    // 2) weights -> bf16 [n][k]
    k_wt<<<dim3(16, 16, 2), dim3(32, 8), 0, stream>>>(W1, Wg, W1t, Wgt);

    // 3) h = PReLU(BN(text@W1 + b1))   [weight-stationary, fp32 A inline-cvt]
    k_gemm_w<1><<<256, 512, 0, stream>>>(text, W1t, h_bf, b1, gamma, beta, rmean, rvar, alpha1);

    // 4) xws = h@Wg                    [weight-stationary, depth-2 prefetch]
    k_gemm_w<2><<<256, 512, 0, stream>>>(h_bf, Wgt, xws, nullptr, nullptr, nullptr, nullptr, nullptr, nullptr);

    // 5) fused gather (deg-weighted) + epilogue + L2 norm + residual
    k_gather_final<<<NN / 4, 256, 0, stream>>>(offs, csr, xws, dinv, bg, alpha2, text, out);
}